// Round 8
// baseline (319.467 us; speedup 1.0000x reference)
//
#include <hip/hip_runtime.h>

#define NN 50000
#define CAP 32          // per-node bin capacity; overflow handled correctly
#define OVF_CAP 4096
#define SUBW 6250       // sub-range width: NN / 8 ranges per relation

__device__ __forceinline__ unsigned short f2bf(float f) {
    unsigned u = __float_as_uint(f);
    u += 0x7fffu + ((u >> 16) & 1u);           // round-to-nearest-even
    return (unsigned short)(u >> 16);
}
__device__ __forceinline__ float bf2f(unsigned short u) {
    return __uint_as_float(((unsigned)u) << 16);
}

// fp32 -> bf16 row copy (n4 = count of float4s)
__global__ __launch_bounds__(256) void to_bf16(
    const float* __restrict__ in, unsigned short* __restrict__ out, int n4)
{
    int stride = gridDim.x * blockDim.x;
    for (int i = blockIdx.x * blockDim.x + threadIdx.x; i < n4; i += stride) {
        float4 v = ((const float4*)in)[i];
        ushort4 o;
        o.x = f2bf(v.x); o.y = f2bf(v.y); o.z = f2bf(v.z); o.w = f2bf(v.w);
        ((ushort4*)out)[i] = o;
    }
}

// Range-sharded bin fill, ushort bins, 2 sub-passes per group.
// R7 post-mortem: WRITE 71MB (5.5x the bins footprint) = partial dirty-line
// evictions, because each bin line stays dirty for the whole 72us scan while
// edge-list streams cycle the 4MB L2. Sub-passes cut the instantaneous dirty
// set to 0.4MB/group and a line's dirty lifetime to one sub-pass; ushort
// halves the footprint outright. Groups 0-3 scan ei0, 4-7 ei1.
__global__ __launch_bounds__(256) void bin_fill(
    const int* __restrict__ ei0, int E0,
    const int* __restrict__ ei1, int E1,
    int* __restrict__ deg, unsigned short* __restrict__ bins,
    int2* __restrict__ ovf, int* __restrict__ ovf_cnt)
{
    int grp  = blockIdx.x & 7;
    int lblk = blockIdx.x >> 3;
    int lgrid = gridDim.x >> 3;
    const int* ei; int E; int baseT;
    if (grp < 4) { ei = ei0; E = E0; baseT = 0; }
    else         { ei = ei1; E = E1; baseT = NN; }
    int stride = lgrid * blockDim.x;

    for (int sub = 0; sub < 2; ++sub) {
        int want = (grp & 3) * 2 + sub;        // 8 ranges of SUBW per relation
        for (int t = lblk * blockDim.x + threadIdx.x; t < E; t += stride) {
            int dstv = ei[E + t];
            if (dstv / SUBW == want) {
                int task = baseT + dstv;
                int s = ei[t];
                int r = atomicAdd(&deg[task], 1);
                if (r < CAP) {
                    bins[(size_t)task * CAP + r] = (unsigned short)s;
                } else {
                    int o = atomicAdd(ovf_cnt, 1);
                    if (o < OVF_CAP) ovf[o] = make_int2(task, s);
                }
            }
        }
    }
}

// One (rel,node) task per wave, 4 independent bf16 gather chains; ushort bins.
__global__ __launch_bounds__(256) void aggregate(
    const unsigned short* __restrict__ bins, const int* __restrict__ deg,
    const unsigned short* __restrict__ hb, float* __restrict__ agg)
{
    int lane = threadIdx.x & 63;
    int wid = (blockIdx.x * blockDim.x + threadIdx.x) >> 6;
    int nwaves = (gridDim.x * blockDim.x) >> 6;
    for (int task = wid; task < 2 * NN; task += nwaves) {
        int d = deg[task];
        int m = min(d, CAP);
        int idx = 0;
        if (lane < m) idx = bins[(size_t)task * CAP + lane];
        float a0 = 0.f, a1 = 0.f, a2 = 0.f, a3 = 0.f;
        int t = 0;
        for (; t + 4 <= m; t += 4) {
            int s0 = __shfl(idx, t + 0);
            int s1 = __shfl(idx, t + 1);
            int s2 = __shfl(idx, t + 2);
            int s3 = __shfl(idx, t + 3);
            a0 += bf2f(hb[(size_t)s0 * 64 + lane]);
            a1 += bf2f(hb[(size_t)s1 * 64 + lane]);
            a2 += bf2f(hb[(size_t)s2 * 64 + lane]);
            a3 += bf2f(hb[(size_t)s3 * 64 + lane]);
        }
        for (; t < m; ++t) {
            int s = __shfl(idx, t);
            a0 += bf2f(hb[(size_t)s * 64 + lane]);
        }
        float sum = (a0 + a1) + (a2 + a3);
        agg[(size_t)task * 64 + lane] = sum / (float)max(d, 1);
    }
}

// Overflow fixup on fp32 h (tiny work; agg stays fp32 so atomicAdd works).
__global__ __launch_bounds__(256) void ovf_fix(
    const int2* __restrict__ ovf, const int* __restrict__ ovf_cnt,
    const int* __restrict__ deg, const float* __restrict__ h,
    float* __restrict__ agg)
{
    int cnt = min(*ovf_cnt, OVF_CAP);
    int total = cnt * 64;
    int stride = gridDim.x * blockDim.x;
    for (int t = blockIdx.x * blockDim.x + threadIdx.x; t < total; t += stride) {
        int e = t >> 6, f = t & 63;
        int2 v = ovf[e];
        float val = h[(size_t)v.y * 64 + f] / (float)max(deg[v.x], 1);
        atomicAdd(&agg[(size_t)v.x * 64 + f], val);
    }
}

// hout = relu(mean0@Wl0 + mean1@Wl1 + self@(Wr0+Wr1) + (b0+b1))
// agg0/agg1 fp32; self path from the bf16 mirror (xb / h1b) — halves that read.
#define RST 132
__global__ __launch_bounds__(256) void layer_gemm(
    const float* __restrict__ agg0, const float* __restrict__ agg1,
    const unsigned short* __restrict__ selfb,
    const float* __restrict__ Wl0, const float* __restrict__ Wl1,
    const float* __restrict__ Wr0, const float* __restrict__ Wr1,
    const float* __restrict__ b0, const float* __restrict__ b1,
    float* __restrict__ hout, unsigned short* __restrict__ hb16)
{
    __shared__ float Wch[64 * 64];
    __shared__ float rowsT[64 * RST];
    __shared__ float bias[64];

    int tid = threadIdx.x;
    int base = blockIdx.x * 128;
    if (tid < 64) bias[tid] = b0[tid] + b1[tid];

    int j8 = (tid & 7) * 8;
    int n4 = (tid >> 3) * 4;

    float acc[4][8];
    #pragma unroll
    for (int i = 0; i < 4; i++)
        #pragma unroll
        for (int c = 0; c < 8; c++) acc[i][c] = 0.f;

    for (int chunk = 0; chunk < 3; chunk++) {
        const float* W = (chunk == 0) ? Wl0 : (chunk == 1) ? Wl1 : Wr0;
        __syncthreads();
        #pragma unroll
        for (int r = 0; r < 4; r++) {
            int i = tid + 256 * r;
            float4 w = *(const float4*)&W[i * 4];
            if (chunk == 2) {
                float4 w2 = *(const float4*)&Wr1[i * 4];
                w.x += w2.x; w.y += w2.y; w.z += w2.z; w.w += w2.w;
            }
            *(float4*)&Wch[i * 4] = w;
        }
        if (chunk < 2) {
            const float* src = (chunk == 0) ? agg0 : agg1;
            #pragma unroll
            for (int r = 0; r < 8; r++) {
                int i = tid + 256 * r;
                int node = i >> 4;
                int k4 = (i & 15) * 4;
                float4 v = make_float4(0.f, 0.f, 0.f, 0.f);
                int g = base + node;
                if (g < NN) v = *(const float4*)&src[(size_t)g * 64 + k4];
                rowsT[(k4 + 0) * RST + node] = v.x;
                rowsT[(k4 + 1) * RST + node] = v.y;
                rowsT[(k4 + 2) * RST + node] = v.z;
                rowsT[(k4 + 3) * RST + node] = v.w;
            }
        } else {
            #pragma unroll
            for (int r = 0; r < 8; r++) {
                int i = tid + 256 * r;
                int node = i >> 4;
                int k4 = (i & 15) * 4;
                int g = base + node;
                ushort4 u = make_ushort4(0, 0, 0, 0);
                if (g < NN) u = *(const ushort4*)&selfb[(size_t)g * 64 + k4];
                rowsT[(k4 + 0) * RST + node] = bf2f(u.x);
                rowsT[(k4 + 1) * RST + node] = bf2f(u.y);
                rowsT[(k4 + 2) * RST + node] = bf2f(u.z);
                rowsT[(k4 + 3) * RST + node] = bf2f(u.w);
            }
        }
        __syncthreads();
        #pragma unroll 4
        for (int k = 0; k < 64; k++) {
            float4 wa = *(const float4*)&Wch[k * 64 + j8];
            float4 wb = *(const float4*)&Wch[k * 64 + j8 + 4];
            float4 rv = *(const float4*)&rowsT[k * RST + n4];
            float w[8] = {wa.x, wa.y, wa.z, wa.w, wb.x, wb.y, wb.z, wb.w};
            float rr[4] = {rv.x, rv.y, rv.z, rv.w};
            #pragma unroll
            for (int i = 0; i < 4; i++)
                #pragma unroll
                for (int c = 0; c < 8; c++)
                    acc[i][c] = fmaf(rr[i], w[c], acc[i][c]);
        }
    }

    #pragma unroll
    for (int i = 0; i < 4; i++) {
        int g = base + n4 + i;
        if (g < NN) {
            float4 o1, o2;
            o1.x = fmaxf(acc[i][0] + bias[j8 + 0], 0.f);
            o1.y = fmaxf(acc[i][1] + bias[j8 + 1], 0.f);
            o1.z = fmaxf(acc[i][2] + bias[j8 + 2], 0.f);
            o1.w = fmaxf(acc[i][3] + bias[j8 + 3], 0.f);
            o2.x = fmaxf(acc[i][4] + bias[j8 + 4], 0.f);
            o2.y = fmaxf(acc[i][5] + bias[j8 + 5], 0.f);
            o2.z = fmaxf(acc[i][6] + bias[j8 + 6], 0.f);
            o2.w = fmaxf(acc[i][7] + bias[j8 + 7], 0.f);
            *(float4*)&hout[(size_t)g * 64 + j8]     = o1;
            *(float4*)&hout[(size_t)g * 64 + j8 + 4] = o2;
            if (hb16) {
                ushort4 p0, p1;
                p0.x = f2bf(o1.x); p0.y = f2bf(o1.y); p0.z = f2bf(o1.z); p0.w = f2bf(o1.w);
                p1.x = f2bf(o2.x); p1.y = f2bf(o2.y); p1.z = f2bf(o2.z); p1.w = f2bf(o2.w);
                *(ushort4*)&hb16[(size_t)g * 64 + j8]     = p0;
                *(ushort4*)&hb16[(size_t)g * 64 + j8 + 4] = p1;
            }
        }
    }
}

// out[i,:32] = h[i,:64] @ W + b
__global__ __launch_bounds__(256) void final_gemm(
    const float* __restrict__ h, const float* __restrict__ W,
    const float* __restrict__ b, float* __restrict__ out)
{
    __shared__ float Ws[64 * 32];
    __shared__ float bs[32];
    __shared__ float rows[8][64];

    int tid = threadIdx.x;
    for (int i = tid; i < 2048; i += 256) Ws[i] = W[i];
    if (tid < 32) bs[tid] = b[tid];

    int j = tid & 31;
    int nl = tid >> 5;

    for (int base = blockIdx.x * 8; base < NN; base += gridDim.x * 8) {
        __syncthreads();
        if (tid < 128) {
            int n = tid >> 4, kq = tid & 15;
            int node = base + n;
            float4 v = make_float4(0.f, 0.f, 0.f, 0.f);
            if (node < NN) v = *(const float4*)&h[(size_t)node * 64 + kq * 4];
            *(float4*)&rows[n][kq * 4] = v;
        }
        __syncthreads();

        int node = base + nl;
        if (node < NN) {
            float acc = bs[j];
            #pragma unroll
            for (int k = 0; k < 64; k += 4) {
                float4 rv = *(const float4*)&rows[nl][k];
                acc = fmaf(rv.x, Ws[(k + 0) * 32 + j], acc);
                acc = fmaf(rv.y, Ws[(k + 1) * 32 + j], acc);
                acc = fmaf(rv.z, Ws[(k + 2) * 32 + j], acc);
                acc = fmaf(rv.w, Ws[(k + 3) * 32 + j], acc);
            }
            out[(size_t)node * 32 + j] = acc;
        }
    }
}

extern "C" void kernel_launch(void* const* d_in, const int* in_sizes, int n_in,
                              void* d_out, int out_size, void* d_ws, size_t ws_size,
                              hipStream_t stream)
{
    const float* x    = (const float*)d_in[0];
    const int*   ei0  = (const int*)d_in[1];
    const int*   ei1  = (const int*)d_in[2];
    const float* Wl   = (const float*)d_in[3];   // [2,2,64,64]
    const float* Wr   = (const float*)d_in[4];   // [2,2,64,64]
    const float* bl   = (const float*)d_in[5];   // [2,2,64]
    const float* linW = (const float*)d_in[6];   // [64,32]
    const float* linb = (const float*)d_in[7];   // [32]
    float* out = (float*)d_out;

    int E0 = in_sizes[1] / 2;
    int E1 = in_sizes[2] / 2;

    // Workspace (large, aligned buffers first):
    // [bins 6.4MB us | agg 25.6MB f | h1 12.8MB f | xb 6.4MB us | h1b 6.4MB us |
    //  deg 400KB | ovf_cnt | ovf]  ~58 MB
    unsigned short* bins = (unsigned short*)d_ws;
    float* agg  = (float*)(bins + (size_t)2 * NN * CAP);
    float* agg0 = agg;
    float* agg1 = agg + (size_t)NN * 64;
    float* h1   = agg + (size_t)2 * NN * 64;
    unsigned short* xb  = (unsigned short*)(h1 + (size_t)NN * 64);
    unsigned short* h1b = xb + (size_t)NN * 64;
    int*  deg     = (int*)(h1b + (size_t)NN * 64);
    int*  ovf_cnt = deg + 2 * NN;
    int2* ovf     = (int2*)(ovf_cnt + 4);

    dim3 blk(256);
    int ggrid = (NN + 127) / 128;   // 391

    (void)hipMemsetAsync(deg, 0, (2 * NN + 4) * sizeof(int), stream);
    bin_fill<<<2048, blk, 0, stream>>>(ei0, E0, ei1, E1, deg, bins, ovf, ovf_cnt);
    to_bf16<<<1024, blk, 0, stream>>>(x, xb, NN * 16);

    // ---- Layer 0 (gather from xb, self from xb) ----
    aggregate<<<4096, blk, 0, stream>>>(bins, deg, xb, agg);
    ovf_fix<<<64, blk, 0, stream>>>(ovf, ovf_cnt, deg, x, agg);
    layer_gemm<<<ggrid, blk, 0, stream>>>(agg0, agg1, xb,
        Wl + 0, Wl + 4096, Wr + 0, Wr + 4096, bl + 0, bl + 64, h1, h1b);

    // ---- Layer 1 (gather from h1b, self from h1b, hout in h1) ----
    aggregate<<<4096, blk, 0, stream>>>(bins, deg, h1b, agg);
    ovf_fix<<<64, blk, 0, stream>>>(ovf, ovf_cnt, deg, h1, agg);
    layer_gemm<<<ggrid, blk, 0, stream>>>(agg0, agg1, h1b,
        Wl + 8192, Wl + 12288, Wr + 8192, Wr + 12288, bl + 128, bl + 192, h1, (unsigned short*)nullptr);

    // ---- Final projection ----
    final_gemm<<<768, blk, 0, stream>>>(h1, linW, linb, out);
}